// Round 16
// baseline (437.192 us; speedup 1.0000x reference)
//
#include <hip/hip_runtime.h>

static constexpr int D = 96;       // hidden size
static constexpr int G3 = 3 * D;   // 288 gate rows
static constexpr int NSTEPS = 4;   // GGNN propagation steps
static constexpr int NT = 18;      // 288/16 col-tiles per weight matrix
static constexpr int SCAN_BLK = 1024;  // elements per scan block
static constexpr int SLP = 104;    // s-tile LDS row pad (fp16)
static constexpr int PLS = 97;     // plane row stride (dwords)
static constexpr int PLANE = 16 * PLS;

typedef __attribute__((ext_vector_type(8))) _Float16 f16x8;  // 8 fp16 (4 VGPRs)
typedef __attribute__((ext_vector_type(4))) _Float16 f16x4;
typedef __attribute__((ext_vector_type(4))) float f32x4;     // MFMA C/D frag

// A-fragment for mfma_f32_16x16x32_f16 from fp16 row-major [*,96]
__device__ __forceinline__ f16x8 load_a_frag(const _Float16* __restrict__ base,
                                             int r0, int lane, int kc) {
  int row = r0 + (lane & 15);
  int k0 = kc * 32 + ((lane >> 4) << 3);
  return *(const f16x8*)(base + (size_t)row * D + k0);
}

// Swizzled B-fragment: slot (t,kc) holds 64 lanes' f16x8 contiguously (1KB)
__device__ __forceinline__ f16x8 load_b_swz(const _Float16* __restrict__ W,
                                            int t, int kc, int lane) {
  return *(const f16x8*)(W + (((size_t)t * 3 + kc) * 64 + lane) * 8);
}

// ---------- one-time prep ----------

// Fused weights prep: WxF = (Wih@We) fp16-swizzled (computed on the fly),
// WhhF = Whh fp16-swizzled, bxe = Wih@be. Eliminates fp32 Wx buffer + a kernel.
__global__ void prep_weights_kernel(const float* __restrict__ Wih,
                                    const float* __restrict__ Whh,
                                    const float* __restrict__ We,
                                    const float* __restrict__ be,
                                    _Float16* __restrict__ WxF,
                                    _Float16* __restrict__ WhhF,
                                    float* __restrict__ bxe) {
  int idx = blockIdx.x * blockDim.x + threadIdx.x;
  const int SWZ = 2 * NT * 3 * 64;   // 6912 swizzle threads
  if (idx < SWZ) {
    int mat = idx / (NT * 3 * 64);
    int rem = idx - mat * (NT * 3 * 64);
    int t = rem / (3 * 64);
    int rem2 = rem - t * (3 * 64);
    int kc = rem2 >> 6;
    int lane = rem2 & 63;
    int c = t * 16 + (lane & 15);
    int k0 = kc * 32 + ((lane >> 4) << 3);
    f16x8 o;
    if (mat == 0) {
      float a[8] = {0.f, 0.f, 0.f, 0.f, 0.f, 0.f, 0.f, 0.f};
      const float* wr = Wih + (size_t)c * D;
      for (int c2 = 0; c2 < D; ++c2) {
        float wv = wr[c2];
        const float* werow = We + (size_t)c2 * D + k0;
#pragma unroll
        for (int j = 0; j < 8; ++j) a[j] += wv * werow[j];
      }
#pragma unroll
      for (int j = 0; j < 8; ++j) o[j] = (_Float16)a[j];
      *(f16x8*)(WxF + (((size_t)t * 3 + kc) * 64 + lane) * 8) = o;
    } else {
#pragma unroll
      for (int j = 0; j < 8; ++j) o[j] = (_Float16)Whh[(size_t)c * D + k0 + j];
      *(f16x8*)(WhhF + (((size_t)t * 3 + kc) * 64 + lane) * 8) = o;
    }
  } else if (idx < SWZ + G3) {
    int r = idx - SWZ;
    float acc = 0.f;
    const float* wr = Wih + (size_t)r * D;
    for (int c = 0; c < D; ++c) acc += wr[c] * be[c];
    bxe[r] = acc;
  }
}

// ---------- CSR build ----------

__global__ void hist_kernel(const int* __restrict__ dst, int* __restrict__ counts, int E) {
  int e = blockIdx.x * blockDim.x + threadIdx.x;
  if (e < E) atomicAdd(&counts[dst[e]], 1);
}

__global__ void partial_sum_kernel(const int* __restrict__ counts,
                                   int* __restrict__ blk_sums, int n) {
  __shared__ int red[256];
  int base = blockIdx.x * SCAN_BLK;
  int tid = threadIdx.x;
  int s = 0;
#pragma unroll
  for (int j = 0; j < 4; ++j) {
    int i = base + j * 256 + tid;
    if (i < n) s += counts[i];
  }
  red[tid] = s;
  __syncthreads();
  for (int off = 128; off > 0; off >>= 1) {
    if (tid < off) red[tid] += red[tid + off];
    __syncthreads();
  }
  if (tid == 0) blk_sums[blockIdx.x] = red[0];
}

__global__ void scan_offsets_kernel(const int* __restrict__ blk_sums,
                                    int* __restrict__ blk_off,
                                    int* __restrict__ row_ptr, int nb, int n) {
  __shared__ int lds[64];
  int tid = threadIdx.x;
  if (tid < nb) lds[tid] = blk_sums[tid];
  __syncthreads();
  if (tid == 0) {
    int run = 0;
    for (int i = 0; i < nb; ++i) { blk_off[i] = run; run += lds[i]; }
    row_ptr[n] = run;
  }
}

__global__ void block_scan_kernel(const int* __restrict__ counts,
                                  const int* __restrict__ blk_off,
                                  int* __restrict__ row_ptr, int n) {
  __shared__ int red[256];
  int base = blockIdx.x * SCAN_BLK;
  int tid = threadIdx.x;
  int i0 = base + tid * 4;
  int v0 = 0, v1 = 0, v2 = 0, v3 = 0;
  if (i0 + 3 < n) {
    int4 c = *(const int4*)(counts + i0);
    v0 = c.x; v1 = c.y; v2 = c.z; v3 = c.w;
  } else {
    if (i0 < n) v0 = counts[i0];
    if (i0 + 1 < n) v1 = counts[i0 + 1];
    if (i0 + 2 < n) v2 = counts[i0 + 2];
  }
  int tsum = v0 + v1 + v2 + v3;
  red[tid] = tsum;
  __syncthreads();
  for (int off = 1; off < 256; off <<= 1) {
    int t = (tid >= off) ? red[tid - off] : 0;
    __syncthreads();
    red[tid] += t;
    __syncthreads();
  }
  int excl = blk_off[blockIdx.x] + red[tid] - tsum;
  if (i0 < n) row_ptr[i0] = excl;
  if (i0 + 1 < n) row_ptr[i0 + 1] = excl + v0;
  if (i0 + 2 < n) row_ptr[i0 + 2] = excl + v0 + v1;
  if (i0 + 3 < n) row_ptr[i0 + 3] = excl + v0 + v1 + v2;
}

// Phase A of two-level fill: route edges into per-bucket staging runs.
// Tail: grid-stride convert of x -> fp16 h (independent work, saves a launch).
__global__ void route_kernel(const int* __restrict__ src, const int* __restrict__ dst,
                             const int* __restrict__ row_ptr,
                             int* __restrict__ bucket_fill,
                             unsigned* __restrict__ stage, int E, int n,
                             const float* __restrict__ x,
                             _Float16* __restrict__ hA, int total4) {
  __shared__ int cnt[64], gbase[64], rpb[64];
  int tid = threadIdx.x;              // 256
  int base = blockIdx.x * 1024;
  if (tid < 64) {
    cnt[tid] = 0;
    int node = tid << 10;
    rpb[tid] = row_ptr[node < n ? node : n];
  }
  __syncthreads();
  int b[4], lp[4], sv[4], dl[4];
#pragma unroll
  for (int j = 0; j < 4; ++j) {
    int e = base + tid * 4 + j;
    if (e < E) {
      sv[j] = src[e];
      int d = dst[e];
      b[j] = d >> 10;
      dl[j] = d & 1023;
      lp[j] = atomicAdd(&cnt[b[j]], 1);
    } else {
      b[j] = -1;
    }
  }
  __syncthreads();
  if (tid < 64) {
    int c = cnt[tid];
    gbase[tid] = (c > 0) ? atomicAdd(&bucket_fill[tid], c) : 0;
  }
  __syncthreads();
#pragma unroll
  for (int j = 0; j < 4; ++j) {
    if (b[j] >= 0) {
      int pos = rpb[b[j]] + gbase[b[j]] + lp[j];
      stage[pos] = (unsigned)sv[j] | ((unsigned)dl[j] << 16);
    }
  }
  // tail: convert x (fp32) -> hA (fp16)
  for (int i = blockIdx.x * blockDim.x + threadIdx.x; i < total4;
       i += gridDim.x * blockDim.x) {
    float4 v = ((const float4*)x)[i];
    f16x4 o;
    o[0] = (_Float16)v.x; o[1] = (_Float16)v.y;
    o[2] = (_Float16)v.z; o[3] = (_Float16)v.w;
    *(f16x4*)(hA + (size_t)i * 4) = o;
  }
}

// Phase B: one block per bucket; scatter within the bucket's ~32KB csr window,
// then SORT each row's src list ascending (insertion sort, window L2-resident).
// Sorted rows make the per-step gather sweep h in ascending order ->
// cross-block temporal locality -> XCD L2 hits instead of HBM line fetches.
// Also makes csr content deterministic.
__global__ void local_fill_kernel(const unsigned* __restrict__ stage,
                                  const int* __restrict__ row_ptr,
                                  unsigned short* __restrict__ csr_src, int n) {
  __shared__ int rp[1024];
  __shared__ int lf[1024];
  int b = blockIdx.x;
  int node0 = b << 10;
  int nn = n - node0; if (nn > 1024) nn = 1024;
  int tid = threadIdx.x;              // 1024
  if (tid < nn) { rp[tid] = row_ptr[node0 + tid]; lf[tid] = 0; }
  __syncthreads();
  int ebeg = row_ptr[node0];
  int eend = row_ptr[node0 + nn];
  for (int i = ebeg + tid; i < eend; i += 1024) {
    unsigned p = stage[i];
    int dl = p >> 16;
    int s = p & 0xFFFF;
    int pos = rp[dl] + atomicAdd(&lf[dl], 1);
    csr_src[pos] = (unsigned short)s;
  }
  __syncthreads();
  if (tid < nn) {
    int b0 = rp[tid];
    int e0 = (tid + 1 < nn) ? rp[tid + 1] : eend;
    for (int i = b0 + 1; i < e0; ++i) {
      unsigned short key = csr_src[i];
      int j = i - 1;
      while (j >= b0 && csr_src[j] > key) { csr_src[j + 1] = csr_src[j]; --j; }
      csr_src[j + 1] = key;
    }
  }
}

// ---------- fused per-step kernel (R12/R15 config: best measured, 57.5us) ----------

__device__ __forceinline__ void gru_epilogue(const float* lds,
                                             const _Float16* __restrict__ h,
                                             _Float16* __restrict__ hout,
                                             const int* __restrict__ row_ptr,
                                             const float* __restrict__ bxe,
                                             const float* __restrict__ bih,
                                             const float* __restrict__ bhh,
                                             int base_row, int tid) {
#pragma unroll
  for (int j = 0; j < 4; ++j) {
    int e = tid + j * 384;
    int row = e / D;
    int col = e - row * D;
    int grow = base_row + row;
    int a = row * PLS + col;
    float degf = (float)(row_ptr[grow + 1] - row_ptr[grow]);
    float R  = lds[a] + lds[PLANE + a];
    float Z  = lds[2 * PLANE + a] + lds[3 * PLANE + a];
    float XN = lds[4 * PLANE + a];
    float HN = lds[5 * PLANE + a];
    float rg = 1.0f / (1.0f + __expf(-(R + bih[col] + bhh[col] + degf * bxe[col])));
    float zg = 1.0f / (1.0f + __expf(-(Z + bih[D + col] + bhh[D + col] + degf * bxe[D + col])));
    float ng = tanhf(XN + bih[2 * D + col] + degf * bxe[2 * D + col] + rg * (HN + bhh[2 * D + col]));
    float hv = (float)h[(size_t)grow * D + col];
    hout[(size_t)grow * D + col] = (_Float16)((1.0f - zg) * ng + zg * hv);
  }
}

__global__ __launch_bounds__(384) void gru_fused_kernel(
    const _Float16* __restrict__ h, _Float16* __restrict__ hout,
    const int* __restrict__ row_ptr, const unsigned short* __restrict__ csr_src,
    const _Float16* __restrict__ WxF, const _Float16* __restrict__ WhhF,
    const float* __restrict__ bxe, const float* __restrict__ bih,
    const float* __restrict__ bhh, int n) {
  __shared__ float lds[6 * PLANE];                    // 37.2 KB total
  _Float16* sl = (_Float16*)&lds[4 * PLANE];          // s tile aliases planes 4/5
  int r0 = blockIdx.x << 5;   // 32 rows per block
  int tid = threadIdx.x;
  int w = tid >> 6;
  int lane = tid & 63;

  // ---- phase 1: gather (12 threads/row, one f16x8 chunk each; 8-deep MLP) ----
  {
    int row = tid / 12;        // 0..31
    int part = tid - row * 12; // chunk of 8 fp16
    int grow = r0 + row;
    float acc[8];
#pragma unroll
    for (int j = 0; j < 8; ++j) acc[j] = 0.f;
    if (grow < n) {
      int beg = row_ptr[grow], end = row_ptr[grow + 1];
      const _Float16* hp = h + (size_t)part * 8;
      int e = beg;
      for (; e + 7 < end; e += 8) {
        f16x8 v0 = *(const f16x8*)(hp + (size_t)csr_src[e] * D);
        f16x8 v1 = *(const f16x8*)(hp + (size_t)csr_src[e + 1] * D);
        f16x8 v2 = *(const f16x8*)(hp + (size_t)csr_src[e + 2] * D);
        f16x8 v3 = *(const f16x8*)(hp + (size_t)csr_src[e + 3] * D);
        f16x8 v4 = *(const f16x8*)(hp + (size_t)csr_src[e + 4] * D);
        f16x8 v5 = *(const f16x8*)(hp + (size_t)csr_src[e + 5] * D);
        f16x8 v6 = *(const f16x8*)(hp + (size_t)csr_src[e + 6] * D);
        f16x8 v7 = *(const f16x8*)(hp + (size_t)csr_src[e + 7] * D);
#pragma unroll
        for (int j = 0; j < 8; ++j)
          acc[j] += (((float)v0[j] + (float)v1[j]) + ((float)v2[j] + (float)v3[j])) +
                    (((float)v4[j] + (float)v5[j]) + ((float)v6[j] + (float)v7[j]));
      }
      if (e + 3 < end) {
        f16x8 v0 = *(const f16x8*)(hp + (size_t)csr_src[e] * D);
        f16x8 v1 = *(const f16x8*)(hp + (size_t)csr_src[e + 1] * D);
        f16x8 v2 = *(const f16x8*)(hp + (size_t)csr_src[e + 2] * D);
        f16x8 v3 = *(const f16x8*)(hp + (size_t)csr_src[e + 3] * D);
#pragma unroll
        for (int j = 0; j < 8; ++j)
          acc[j] += ((float)v0[j] + (float)v1[j]) + ((float)v2[j] + (float)v3[j]);
        e += 4;
      }
      for (; e < end; ++e) {
        f16x8 v = *(const f16x8*)(hp + (size_t)csr_src[e] * D);
#pragma unroll
        for (int j = 0; j < 8; ++j) acc[j] += (float)v[j];
      }
    }
    f16x8 o;
#pragma unroll
    for (int j = 0; j < 8; ++j) o[j] = (_Float16)acc[j];
    *(f16x8*)&sl[row * SLP + part * 8] = o;
  }
  __syncthreads();

  // ---- phase 2: A-fragment loads ----
  const int opS = (w < 3) ? 1 : 0;
  const _Float16* WF = opS ? WxF : WhhF;
  const int wg = opS ? w : (w - 3);        // 0=R, 1=Z, 2=N
  const int t0 = wg * 6;                   // col-tiles t0..t0+5
  const int plane = wg * 2 + (opS ? 0 : 1);

  f16x8 a0[3], a1[3];
  if (opS) {
#pragma unroll
    for (int kc = 0; kc < 3; ++kc) {
      int k0 = kc * 32 + ((lane >> 4) << 3);
      a0[kc] = *(const f16x8*)&sl[(lane & 15) * SLP + k0];
      a1[kc] = *(const f16x8*)&sl[(16 + (lane & 15)) * SLP + k0];
    }
  } else {
#pragma unroll
    for (int kc = 0; kc < 3; ++kc) {
      a0[kc] = load_a_frag(h, r0, lane, kc);
      a1[kc] = load_a_frag(h, r0 + 16, lane, kc);
    }
  }
  __syncthreads();   // sl fully read (in regs) before planes 4/5 are overwritten

  f32x4 acc0[6], acc1[6];
#pragma unroll
  for (int t = 0; t < 6; ++t) {
    acc0[t] = (f32x4){0.f, 0.f, 0.f, 0.f};
    acc1[t] = (f32x4){0.f, 0.f, 0.f, 0.f};
  }

#pragma unroll
  for (int ct = 0; ct < 6; ++ct)
#pragma unroll
    for (int kc = 0; kc < 3; ++kc) {
      f16x8 b = load_b_swz(WF, t0 + ct, kc, lane);
      acc0[ct] = __builtin_amdgcn_mfma_f32_16x16x32_f16(a0[kc], b, acc0[ct], 0, 0, 0);
      acc1[ct] = __builtin_amdgcn_mfma_f32_16x16x32_f16(a1[kc], b, acc1[ct], 0, 0, 0);
    }

  // ---- phase 3: epilogues (C/D layout: col=lane&15, row=(lane>>4)*4+q) ----
  int col_l = lane & 15;
  int rq = (lane >> 4) << 2;
#pragma unroll
  for (int ct = 0; ct < 6; ++ct)
#pragma unroll
    for (int q = 0; q < 4; ++q)
      lds[plane * PLANE + (rq + q) * PLS + ct * 16 + col_l] = acc0[ct][q];
  __syncthreads();
  gru_epilogue(lds, h, hout, row_ptr, bxe, bih, bhh, r0, tid);
  __syncthreads();
  if (r0 + 16 < n) {
#pragma unroll
    for (int ct = 0; ct < 6; ++ct)
#pragma unroll
      for (int q = 0; q < 4; ++q)
        lds[plane * PLANE + (rq + q) * PLS + ct * 16 + col_l] = acc1[ct][q];
    __syncthreads();
    gru_epilogue(lds, h, hout, row_ptr, bxe, bih, bhh, r0 + 16, tid);
  }
}

// logits[i,c] = sum_k elu(h[i,k]) * Wfc[c,k] + bfc[c]
__global__ void head_kernel(const _Float16* __restrict__ h,
                            const float* __restrict__ Wfc,
                            const float* __restrict__ bfc,
                            float* __restrict__ out,
                            int n, int C) {
  int idx = blockIdx.x * blockDim.x + threadIdx.x;
  if (idx >= n * C) return;
  int i = idx / C;
  int c = idx - i * C;
  const _Float16* hr = h + (size_t)i * D;
  const float* wr = Wfc + (size_t)c * D;
  float acc = bfc[c];
#pragma unroll 8
  for (int k = 0; k < D; ++k) {
    float hv = (float)hr[k];
    float e = hv > 0.0f ? hv : (__expf(hv) - 1.0f);
    acc += e * wr[k];
  }
  out[idx] = acc;
}

extern "C" void kernel_launch(void* const* d_in, const int* in_sizes, int n_in,
                              void* d_out, int out_size, void* d_ws, size_t ws_size,
                              hipStream_t stream) {
  const float* x    = (const float*)d_in[0];
  const int*   src  = (const int*)d_in[1];
  const int*   dst  = (const int*)d_in[2];
  const float* W_e  = (const float*)d_in[3];
  const float* b_e  = (const float*)d_in[4];
  const float* W_ih = (const float*)d_in[5];
  const float* W_hh = (const float*)d_in[6];
  const float* b_ih = (const float*)d_in[7];
  const float* b_hh = (const float*)d_in[8];
  const float* W_fc = (const float*)d_in[9];
  const float* b_fc = (const float*)d_in[10];

  const int n = in_sizes[0] / D;   // 50000
  const int E = in_sizes[1];       // 800000
  const int C = out_size / n;      // 10

  // ws layout (fp16 state; Wx buffer removed):
  _Float16* hA = (_Float16*)d_ws;                 // n*D fp16
  _Float16* hB = hA + (size_t)n * D;              // n*D fp16
  _Float16* WxF  = hB + (size_t)n * D;            // G3*D fp16 swizzled
  _Float16* WhhF = WxF + (size_t)G3 * D;
  float* bxe   = (float*)(WhhF + (size_t)G3 * D); // G3 fp32
  int* counts  = (int*)(bxe + G3);                // n
  int* bucket_fill = counts + n;                  // 64 (n slot for memset ease)
  int* row_ptr = bucket_fill + n;                 // n+1
  unsigned short* csr_src = (unsigned short*)(row_ptr + (n + 1));  // E u16
  int* blk_sums = (int*)(csr_src + E);            // <=64
  int* blk_off  = blk_sums + 64;                  // <=64
  unsigned* stage = (unsigned*)(blk_off + 64);    // E u32 packed (src | dl<<16)

  const int threads = 256;
  const int nb = (n + SCAN_BLK - 1) / SCAN_BLK;   // 49 scan blocks
  const int NB = (n + 1023) >> 10;                // 49 dst buckets
  const int total4 = n * D / 4;

  (void)hipMemsetAsync(counts, 0, (size_t)2 * n * sizeof(int), stream);
  hist_kernel<<<(E + threads - 1) / threads, threads, 0, stream>>>(dst, counts, E);
  partial_sum_kernel<<<nb, 256, 0, stream>>>(counts, blk_sums, n);
  scan_offsets_kernel<<<1, 64, 0, stream>>>(blk_sums, blk_off, row_ptr, nb, n);
  block_scan_kernel<<<nb, 256, 0, stream>>>(counts, blk_off, row_ptr, n);
  route_kernel<<<(E + 1023) / 1024, 256, 0, stream>>>(src, dst, row_ptr,
                                                      bucket_fill, stage, E, n,
                                                      x, hA, total4);
  local_fill_kernel<<<NB, 1024, 0, stream>>>(stage, row_ptr, csr_src, n);
  prep_weights_kernel<<<(2 * NT * 3 * 64 + G3 + threads - 1) / threads, threads, 0,
                        stream>>>(W_ih, W_hh, W_e, b_e, WxF, WhhF, bxe);

  const int gridG = (n + 31) / 32;   // 32 rows per block

  const _Float16* hcur = hA;
  _Float16* hnext = hB;
  for (int step = 0; step < NSTEPS; ++step) {
    gru_fused_kernel<<<gridG, 384, 0, stream>>>(hcur, hnext, row_ptr, csr_src,
                                                WxF, WhhF, bxe, b_ih, b_hh, n);
    const _Float16* t = hcur; hcur = hnext; hnext = (_Float16*)t;
  }

  const int gridH = (n * C + threads - 1) / threads;
  head_kernel<<<gridH, threads, 0, stream>>>(hcur, W_fc, b_fc, (float*)d_out, n, C);
}

// Round 17
// 301.966 us; speedup vs baseline: 1.4478x; 1.4478x over previous
//
#include <hip/hip_runtime.h>

static constexpr int D = 96;       // hidden size
static constexpr int G3 = 3 * D;   // 288 gate rows
static constexpr int NSTEPS = 4;   // GGNN propagation steps
static constexpr int NT = 18;      // 288/16 col-tiles per weight matrix
static constexpr int SLP = 104;    // s-tile LDS row pad (fp16)
static constexpr int PLS = 97;     // plane row stride (dwords)
static constexpr int PLANE = 16 * PLS;
static constexpr int CAP = 24576;  // staging capacity per 1024-node bucket (avg 16.3K, +6sigma ~17.1K)

typedef __attribute__((ext_vector_type(8))) _Float16 f16x8;  // 8 fp16 (4 VGPRs)
typedef __attribute__((ext_vector_type(4))) _Float16 f16x4;
typedef __attribute__((ext_vector_type(4))) float f32x4;     // MFMA C/D frag

// A-fragment for mfma_f32_16x16x32_f16 from fp16 row-major [*,96]
__device__ __forceinline__ f16x8 load_a_frag(const _Float16* __restrict__ base,
                                             int r0, int lane, int kc) {
  int row = r0 + (lane & 15);
  int k0 = kc * 32 + ((lane >> 4) << 3);
  return *(const f16x8*)(base + (size_t)row * D + k0);
}

// Swizzled B-fragment: slot (t,kc) holds 64 lanes' f16x8 contiguously (1KB)
__device__ __forceinline__ f16x8 load_b_swz(const _Float16* __restrict__ W,
                                            int t, int kc, int lane) {
  return *(const f16x8*)(W + (((size_t)t * 3 + kc) * 64 + lane) * 8);
}

// ---------- one-time prep ----------

// Fused weights prep: WxF = (Wih@We) fp16-swizzled (computed on the fly),
// WhhF = Whh fp16-swizzled, bxe = Wih@be.
__global__ void prep_weights_kernel(const float* __restrict__ Wih,
                                    const float* __restrict__ Whh,
                                    const float* __restrict__ We,
                                    const float* __restrict__ be,
                                    _Float16* __restrict__ WxF,
                                    _Float16* __restrict__ WhhF,
                                    float* __restrict__ bxe) {
  int idx = blockIdx.x * blockDim.x + threadIdx.x;
  const int SWZ = 2 * NT * 3 * 64;   // 6912 swizzle threads
  if (idx < SWZ) {
    int mat = idx / (NT * 3 * 64);
    int rem = idx - mat * (NT * 3 * 64);
    int t = rem / (3 * 64);
    int rem2 = rem - t * (3 * 64);
    int kc = rem2 >> 6;
    int lane = rem2 & 63;
    int c = t * 16 + (lane & 15);
    int k0 = kc * 32 + ((lane >> 4) << 3);
    f16x8 o;
    if (mat == 0) {
      float a[8] = {0.f, 0.f, 0.f, 0.f, 0.f, 0.f, 0.f, 0.f};
      const float* wr = Wih + (size_t)c * D;
      for (int c2 = 0; c2 < D; ++c2) {
        float wv = wr[c2];
        const float* werow = We + (size_t)c2 * D + k0;
#pragma unroll
        for (int j = 0; j < 8; ++j) a[j] += wv * werow[j];
      }
#pragma unroll
      for (int j = 0; j < 8; ++j) o[j] = (_Float16)a[j];
      *(f16x8*)(WxF + (((size_t)t * 3 + kc) * 64 + lane) * 8) = o;
    } else {
#pragma unroll
      for (int j = 0; j < 8; ++j) o[j] = (_Float16)Whh[(size_t)c * D + k0 + j];
      *(f16x8*)(WhhF + (((size_t)t * 3 + kc) * 64 + lane) * 8) = o;
    }
  } else if (idx < SWZ + G3) {
    int r = idx - SWZ;
    float acc = 0.f;
    const float* wr = Wih + (size_t)r * D;
    for (int c = 0; c < D; ++c) acc += wr[c] * be[c];
    bxe[r] = acc;
  }
}

// ---------- CSR build (bucketed; no global hist/scan needed) ----------

// Route edges into fixed-capacity per-bucket staging regions (b*CAP).
// Tail: grid-stride convert of x -> fp16 h.
__global__ void route_kernel(const int* __restrict__ src, const int* __restrict__ dst,
                             int* __restrict__ bucket_fill,
                             unsigned* __restrict__ stage, int E,
                             const float* __restrict__ x,
                             _Float16* __restrict__ hA, int total4) {
  __shared__ int cnt[64], gbase[64];
  int tid = threadIdx.x;              // 256
  int base = blockIdx.x * 1024;
  if (tid < 64) cnt[tid] = 0;
  __syncthreads();
  int b[4], lp[4], sv[4], dl[4];
#pragma unroll
  for (int j = 0; j < 4; ++j) {
    int e = base + tid * 4 + j;
    if (e < E) {
      sv[j] = src[e];
      int d = dst[e];
      b[j] = d >> 10;
      dl[j] = d & 1023;
      lp[j] = atomicAdd(&cnt[b[j]], 1);
    } else {
      b[j] = -1;
    }
  }
  __syncthreads();
  if (tid < 64) {
    int c = cnt[tid];
    gbase[tid] = (c > 0) ? atomicAdd(&bucket_fill[tid], c) : 0;
  }
  __syncthreads();
#pragma unroll
  for (int j = 0; j < 4; ++j) {
    if (b[j] >= 0) {
      int pos = b[j] * CAP + gbase[b[j]] + lp[j];
      stage[pos] = (unsigned)sv[j] | ((unsigned)dl[j] << 16);
    }
  }
  // tail: convert x (fp32) -> hA (fp16)
  for (int i = blockIdx.x * blockDim.x + threadIdx.x; i < total4;
       i += gridDim.x * blockDim.x) {
    float4 v = ((const float4*)x)[i];
    f16x4 o;
    o[0] = (_Float16)v.x; o[1] = (_Float16)v.y;
    o[2] = (_Float16)v.z; o[3] = (_Float16)v.w;
    *(f16x4*)(hA + (size_t)i * 4) = o;
  }
}

// Tiny serial scan of bucket counts -> bucket bases; also row_ptr[n] = E.
__global__ void bucket_scan_kernel(const int* __restrict__ bucket_fill,
                                   int* __restrict__ bucket_base,
                                   int* __restrict__ row_ptr, int NB, int n, int E) {
  if (threadIdx.x == 0) {
    int run = 0;
    for (int i = 0; i < NB; ++i) { bucket_base[i] = run; run += bucket_fill[i]; }
    bucket_base[NB] = run;
    row_ptr[n] = E;
  }
}

// Per bucket: LDS histogram of staged edges -> LDS scan -> write row_ptr
// segment AND scatter csr_src, all with LDS counters (csr window L2-local).
__global__ void local_fill_kernel(const unsigned* __restrict__ stage,
                                  const int* __restrict__ bucket_fill,
                                  const int* __restrict__ bucket_base,
                                  int* __restrict__ row_ptr,
                                  unsigned short* __restrict__ csr_src, int n) {
  __shared__ int hc[1024];
  __shared__ int sc[1024];
  int b = blockIdx.x;
  int node0 = b << 10;
  int nn = n - node0; if (nn > 1024) nn = 1024;
  int tid = threadIdx.x;              // 1024
  int cnt_b = bucket_fill[b];
  int gb = bucket_base[b];
  const unsigned* sb = stage + (size_t)b * CAP;
  hc[tid] = 0;
  __syncthreads();
  for (int i = tid; i < cnt_b; i += 1024)
    atomicAdd(&hc[(int)(sb[i] >> 16)], 1);
  __syncthreads();
  sc[tid] = hc[tid];
  __syncthreads();
  for (int off = 1; off < 1024; off <<= 1) {
    int v = (tid >= off) ? sc[tid - off] : 0;
    __syncthreads();
    sc[tid] += v;
    __syncthreads();
  }
  int excl = sc[tid] - hc[tid];
  __syncthreads();
  sc[tid] = excl;
  if (tid < nn) row_ptr[node0 + tid] = gb + excl;
  hc[tid] = 0;
  __syncthreads();
  for (int i = tid; i < cnt_b; i += 1024) {
    unsigned p = sb[i];
    int dl = (int)(p >> 16);
    int pos = gb + sc[dl] + atomicAdd(&hc[dl], 1);
    csr_src[pos] = (unsigned short)(p & 0xFFFF);
  }
}

// ---------- fused per-step kernel (R12/R15 config: best measured, 57.5us) ----------

__device__ __forceinline__ void gru_epilogue(const float* lds,
                                             const _Float16* __restrict__ h,
                                             _Float16* __restrict__ hout,
                                             const int* __restrict__ row_ptr,
                                             const float* __restrict__ bxe,
                                             const float* __restrict__ bih,
                                             const float* __restrict__ bhh,
                                             int base_row, int tid) {
#pragma unroll
  for (int j = 0; j < 4; ++j) {
    int e = tid + j * 384;
    int row = e / D;
    int col = e - row * D;
    int grow = base_row + row;
    int a = row * PLS + col;
    float degf = (float)(row_ptr[grow + 1] - row_ptr[grow]);
    float R  = lds[a] + lds[PLANE + a];
    float Z  = lds[2 * PLANE + a] + lds[3 * PLANE + a];
    float XN = lds[4 * PLANE + a];
    float HN = lds[5 * PLANE + a];
    float rg = 1.0f / (1.0f + __expf(-(R + bih[col] + bhh[col] + degf * bxe[col])));
    float zg = 1.0f / (1.0f + __expf(-(Z + bih[D + col] + bhh[D + col] + degf * bxe[D + col])));
    float ng = tanhf(XN + bih[2 * D + col] + degf * bxe[2 * D + col] + rg * (HN + bhh[2 * D + col]));
    float hv = (float)h[(size_t)grow * D + col];
    hout[(size_t)grow * D + col] = (_Float16)((1.0f - zg) * ng + zg * hv);
  }
}

__global__ __launch_bounds__(384) void gru_fused_kernel(
    const _Float16* __restrict__ h, _Float16* __restrict__ hout,
    const int* __restrict__ row_ptr, const unsigned short* __restrict__ csr_src,
    const _Float16* __restrict__ WxF, const _Float16* __restrict__ WhhF,
    const float* __restrict__ bxe, const float* __restrict__ bih,
    const float* __restrict__ bhh, int n) {
  __shared__ float lds[6 * PLANE];                    // 37.2 KB total
  _Float16* sl = (_Float16*)&lds[4 * PLANE];          // s tile aliases planes 4/5
  int r0 = blockIdx.x << 5;   // 32 rows per block
  int tid = threadIdx.x;
  int w = tid >> 6;
  int lane = tid & 63;

  // ---- phase 1: gather (12 threads/row, one f16x8 chunk each; 8-deep MLP) ----
  {
    int row = tid / 12;        // 0..31
    int part = tid - row * 12; // chunk of 8 fp16
    int grow = r0 + row;
    float acc[8];
#pragma unroll
    for (int j = 0; j < 8; ++j) acc[j] = 0.f;
    if (grow < n) {
      int beg = row_ptr[grow], end = row_ptr[grow + 1];
      const _Float16* hp = h + (size_t)part * 8;
      int e = beg;
      for (; e + 7 < end; e += 8) {
        f16x8 v0 = *(const f16x8*)(hp + (size_t)csr_src[e] * D);
        f16x8 v1 = *(const f16x8*)(hp + (size_t)csr_src[e + 1] * D);
        f16x8 v2 = *(const f16x8*)(hp + (size_t)csr_src[e + 2] * D);
        f16x8 v3 = *(const f16x8*)(hp + (size_t)csr_src[e + 3] * D);
        f16x8 v4 = *(const f16x8*)(hp + (size_t)csr_src[e + 4] * D);
        f16x8 v5 = *(const f16x8*)(hp + (size_t)csr_src[e + 5] * D);
        f16x8 v6 = *(const f16x8*)(hp + (size_t)csr_src[e + 6] * D);
        f16x8 v7 = *(const f16x8*)(hp + (size_t)csr_src[e + 7] * D);
#pragma unroll
        for (int j = 0; j < 8; ++j)
          acc[j] += (((float)v0[j] + (float)v1[j]) + ((float)v2[j] + (float)v3[j])) +
                    (((float)v4[j] + (float)v5[j]) + ((float)v6[j] + (float)v7[j]));
      }
      if (e + 3 < end) {
        f16x8 v0 = *(const f16x8*)(hp + (size_t)csr_src[e] * D);
        f16x8 v1 = *(const f16x8*)(hp + (size_t)csr_src[e + 1] * D);
        f16x8 v2 = *(const f16x8*)(hp + (size_t)csr_src[e + 2] * D);
        f16x8 v3 = *(const f16x8*)(hp + (size_t)csr_src[e + 3] * D);
#pragma unroll
        for (int j = 0; j < 8; ++j)
          acc[j] += ((float)v0[j] + (float)v1[j]) + ((float)v2[j] + (float)v3[j]);
        e += 4;
      }
      for (; e < end; ++e) {
        f16x8 v = *(const f16x8*)(hp + (size_t)csr_src[e] * D);
#pragma unroll
        for (int j = 0; j < 8; ++j) acc[j] += (float)v[j];
      }
    }
    f16x8 o;
#pragma unroll
    for (int j = 0; j < 8; ++j) o[j] = (_Float16)acc[j];
    *(f16x8*)&sl[row * SLP + part * 8] = o;
  }
  __syncthreads();

  // ---- phase 2: A-fragment loads ----
  const int opS = (w < 3) ? 1 : 0;
  const _Float16* WF = opS ? WxF : WhhF;
  const int wg = opS ? w : (w - 3);        // 0=R, 1=Z, 2=N
  const int t0 = wg * 6;                   // col-tiles t0..t0+5
  const int plane = wg * 2 + (opS ? 0 : 1);

  f16x8 a0[3], a1[3];
  if (opS) {
#pragma unroll
    for (int kc = 0; kc < 3; ++kc) {
      int k0 = kc * 32 + ((lane >> 4) << 3);
      a0[kc] = *(const f16x8*)&sl[(lane & 15) * SLP + k0];
      a1[kc] = *(const f16x8*)&sl[(16 + (lane & 15)) * SLP + k0];
    }
  } else {
#pragma unroll
    for (int kc = 0; kc < 3; ++kc) {
      a0[kc] = load_a_frag(h, r0, lane, kc);
      a1[kc] = load_a_frag(h, r0 + 16, lane, kc);
    }
  }
  __syncthreads();   // sl fully read (in regs) before planes 4/5 are overwritten

  f32x4 acc0[6], acc1[6];
#pragma unroll
  for (int t = 0; t < 6; ++t) {
    acc0[t] = (f32x4){0.f, 0.f, 0.f, 0.f};
    acc1[t] = (f32x4){0.f, 0.f, 0.f, 0.f};
  }

#pragma unroll
  for (int ct = 0; ct < 6; ++ct)
#pragma unroll
    for (int kc = 0; kc < 3; ++kc) {
      f16x8 b = load_b_swz(WF, t0 + ct, kc, lane);
      acc0[ct] = __builtin_amdgcn_mfma_f32_16x16x32_f16(a0[kc], b, acc0[ct], 0, 0, 0);
      acc1[ct] = __builtin_amdgcn_mfma_f32_16x16x32_f16(a1[kc], b, acc1[ct], 0, 0, 0);
    }

  // ---- phase 3: epilogues (C/D layout: col=lane&15, row=(lane>>4)*4+q) ----
  int col_l = lane & 15;
  int rq = (lane >> 4) << 2;
#pragma unroll
  for (int ct = 0; ct < 6; ++ct)
#pragma unroll
    for (int q = 0; q < 4; ++q)
      lds[plane * PLANE + (rq + q) * PLS + ct * 16 + col_l] = acc0[ct][q];
  __syncthreads();
  gru_epilogue(lds, h, hout, row_ptr, bxe, bih, bhh, r0, tid);
  __syncthreads();
  if (r0 + 16 < n) {
#pragma unroll
    for (int ct = 0; ct < 6; ++ct)
#pragma unroll
      for (int q = 0; q < 4; ++q)
        lds[plane * PLANE + (rq + q) * PLS + ct * 16 + col_l] = acc1[ct][q];
    __syncthreads();
    gru_epilogue(lds, h, hout, row_ptr, bxe, bih, bhh, r0 + 16, tid);
  }
}

// logits[i,c] = sum_k elu(h[i,k]) * Wfc[c,k] + bfc[c]
__global__ void head_kernel(const _Float16* __restrict__ h,
                            const float* __restrict__ Wfc,
                            const float* __restrict__ bfc,
                            float* __restrict__ out,
                            int n, int C) {
  int idx = blockIdx.x * blockDim.x + threadIdx.x;
  if (idx >= n * C) return;
  int i = idx / C;
  int c = idx - i * C;
  const _Float16* hr = h + (size_t)i * D;
  const float* wr = Wfc + (size_t)c * D;
  float acc = bfc[c];
#pragma unroll 8
  for (int k = 0; k < D; ++k) {
    float hv = (float)hr[k];
    float e = hv > 0.0f ? hv : (__expf(hv) - 1.0f);
    acc += e * wr[k];
  }
  out[idx] = acc;
}

extern "C" void kernel_launch(void* const* d_in, const int* in_sizes, int n_in,
                              void* d_out, int out_size, void* d_ws, size_t ws_size,
                              hipStream_t stream) {
  const float* x    = (const float*)d_in[0];
  const int*   src  = (const int*)d_in[1];
  const int*   dst  = (const int*)d_in[2];
  const float* W_e  = (const float*)d_in[3];
  const float* b_e  = (const float*)d_in[4];
  const float* W_ih = (const float*)d_in[5];
  const float* W_hh = (const float*)d_in[6];
  const float* b_ih = (const float*)d_in[7];
  const float* b_hh = (const float*)d_in[8];
  const float* W_fc = (const float*)d_in[9];
  const float* b_fc = (const float*)d_in[10];

  const int n = in_sizes[0] / D;   // 50000
  const int E = in_sizes[1];       // 800000
  const int C = out_size / n;      // 10

  // ws layout:
  _Float16* hA = (_Float16*)d_ws;                 // n*D fp16
  _Float16* hB = hA + (size_t)n * D;              // n*D fp16
  _Float16* WxF  = hB + (size_t)n * D;            // G3*D fp16 swizzled
  _Float16* WhhF = WxF + (size_t)G3 * D;
  float* bxe   = (float*)(WhhF + (size_t)G3 * D); // G3 fp32
  int* bucket_fill = (int*)(bxe + G3);            // 64
  int* bucket_base = bucket_fill + 64;            // 65
  int* row_ptr = bucket_base + 65;                // n+1
  unsigned short* csr_src = (unsigned short*)(row_ptr + (n + 1));  // E u16
  unsigned* stage = (unsigned*)(csr_src + E);     // NB*CAP u32 (E even -> aligned)

  const int threads = 256;
  const int NB = (n + 1023) >> 10;                // 49 dst buckets
  const int total4 = n * D / 4;

  (void)hipMemsetAsync(bucket_fill, 0, 64 * sizeof(int), stream);
  route_kernel<<<(E + 1023) / 1024, 256, 0, stream>>>(src, dst, bucket_fill,
                                                      stage, E, x, hA, total4);
  bucket_scan_kernel<<<1, 64, 0, stream>>>(bucket_fill, bucket_base, row_ptr,
                                           NB, n, E);
  local_fill_kernel<<<NB, 1024, 0, stream>>>(stage, bucket_fill, bucket_base,
                                             row_ptr, csr_src, n);
  prep_weights_kernel<<<(2 * NT * 3 * 64 + G3 + threads - 1) / threads, threads, 0,
                        stream>>>(W_ih, W_hh, W_e, b_e, WxF, WhhF, bxe);

  const int gridG = (n + 31) / 32;   // 32 rows per block

  const _Float16* hcur = hA;
  _Float16* hnext = hB;
  for (int step = 0; step < NSTEPS; ++step) {
    gru_fused_kernel<<<gridG, 384, 0, stream>>>(hcur, hnext, row_ptr, csr_src,
                                                WxF, WhhF, bxe, b_ih, b_hh, n);
    const _Float16* t = hcur; hcur = hnext; hnext = (_Float16*)t;
  }

  const int gridH = (n * C + threads - 1) / threads;
  head_kernel<<<gridH, threads, 0, stream>>>(hcur, W_fc, b_fc, (float*)d_out, n, C);
}